// Round 3
// baseline (461.074 us; speedup 1.0000x reference)
//
#include <hip/hip_runtime.h>

#define NN   2048
#define FF   512
#define CC   128
#define WROW 2560
#define INFV 1.0e9f
#define NBLK 512          // sweep blocks (2/CU)
#define NTHR 256
#define BN   4            // v-columns per block
#define P2B  256          // phase-2 blocks
#define DONEV 6000u       // flags2 value when partials are published

#define AL(p)   __hip_atomic_load((p), __ATOMIC_RELAXED, __HIP_MEMORY_SCOPE_AGENT)
#define AS(p,v) __hip_atomic_store((p), (v), __ATOMIC_RELAXED, __HIP_MEMORY_SCOPE_AGENT)

// ws layout: D[2][NN] floats | flags[NBLK] | flags2[NBLK]
// partials are exchanged through the out buffer itself.

// Skew-tolerant flag poll for sweep s (wave0 only, tid<64).
// Accepts {s, s+1}; a block at s+1 implies consensus "continue" at s.
__device__ __forceinline__ unsigned sweep_poll(unsigned* flags, int s) {
    const unsigned expect = (unsigned)s;
    const int lane = threadIdx.x;        // 0..63
    for (;;) {
        bool ok = true; unsigned adv = 0, bits = 0;
        #pragma unroll
        for (int j = 0; j < 8; ++j) {
            unsigned f = AL(&flags[lane * 8 + j]);
            unsigned e = f >> 1;
            bool okj = (e == expect) | (e == expect + 1);
            ok &= okj;
            adv  |= (e == expect + 1) ? 1u : 0u;
            bits |= (e == expect) ? (f & 1u) : 0u;
        }
        if (__all(ok)) {
            unsigned r = (__any(adv) ? 1u : 0u) | (__any(bits) ? 1u : 0u);
            return r;    // chany consensus
        }
        __builtin_amdgcn_s_sleep(1);
    }
}

__device__ __forceinline__ void done_poll(unsigned* flags2) {
    const int lane = threadIdx.x;
    for (;;) {
        bool ok = true;
        #pragma unroll
        for (int j = 0; j < 8; ++j)
            ok &= (AL(&flags2[lane * 8 + j]) == DONEV);
        if (__all(ok)) return;
        __builtin_amdgcn_s_sleep(1);
    }
}

__global__ __launch_bounds__(NTHR, 2)
void bf_gnn_lds(const float* __restrict__ adj,
                const float* __restrict__ emb,
                const float* __restrict__ W,
                const float* __restrict__ bias,
                const int*   __restrict__ srcp,
                float*       __restrict__ out,
                unsigned*    __restrict__ ws_u,
                int out_size)
{
    __shared__ __align__(16) char smem[43008];
    float*    adjT = (float*)smem;               // [NN][BN]          32768 B
    float*    dist = (float*)(smem + 32768);     // [NN]               8192 B
    float*    red  = (float*)(smem + 40960);     // [64][BN]           1024 B
    float*    red2 = (float*)(smem + 41984);     // [16][BN]            256 B
    float*    dcol = (float*)(smem + 42240);     // [BN]
    unsigned* pinfo= (unsigned*)(smem + 42256);  // [1]
    float*    Suf  = (float*)(smem + 42272);     // [CC]                512 B

    const int tid = threadIdx.x;
    const int b   = blockIdx.x;
    const int src = *srcp;

    float*    D0     = (float*)ws_u;             // [2][NN]
    unsigned* flags  = ws_u + 2 * NN;            // [NBLK]
    unsigned* flags2 = ws_u + 2 * NN + NBLK;     // [NBLK]

    // XCD-contiguous v-slice assignment: neighbor slices share cache lines
    const int q  = (b & 7) * 64 + (b >> 3);
    const int vb = q * BN;

    // ---- stage adjacency slice into LDS: adjT[u][vs] = adj[u][vb+vs] ----
    #pragma unroll
    for (int k = 0; k < NN / NTHR; ++k) {
        int u = tid + k * NTHR;
        float4 a = *(const float4*)(adj + (size_t)u * NN + vb);
        *(float4*)(adjT + u * BN) = a;
    }
    #pragma unroll
    for (int k = 0; k < NN / NTHR; ++k) {
        int i = tid + k * NTHR;
        dist[i] = (i == src) ? 0.0f : INFV;
    }
    __syncthreads();

    // per-thread accumulators: v = vb + (tid>>6), c0 = (2*tid)&127
    const int vown  = tid >> 6;
    const int c0    = (2 * tid) & 127;
    const int vglob = vb + vown;
    float dprev_own = 0.0f;
    if (tid < BN) dprev_own = ((vb + tid) == src) ? 0.0f : INFV;

    float acc0, acc1;
    {
        float d0 = (vglob == src) ? 0.0f : INFV;   // distances column 0 = init
        acc0 = d0 * W[(size_t)c0 * WROW + FF];
        acc1 = d0 * W[(size_t)(c0 + 1) * WROW + FF];
    }

    const int vslot = tid & (BN - 1);
    const int g     = tid >> 2;          // 0..63

    int kconv = -1, hneg = 0;

    for (int s = 1; s <= NN; ++s) {
        // W column loads issued early (fold happens later this sweep)
        float w0 = 0.0f, w1 = 0.0f;
        if (s < NN) {
            w0 = W[(size_t)c0 * WROW + FF + s];
            w1 = W[(size_t)(c0 + 1) * WROW + FF + s];
        }
        // ---- min-plus over all u, pure LDS ----
        float m = 4.0e9f;
        #pragma unroll 8
        for (int k = 0; k < NN / 64; ++k) {
            int u = g + 64 * k;
            m = fminf(m, dist[u] + adjT[u * BN + vslot]);
        }
        red[g * BN + vslot] = m;
        __syncthreads();                             // sync A

        unsigned ch = 0;
        if (tid < 64) {                               // wave 0
            int vs = tid & 3, gg = tid >> 2;          // gg 0..15
            float mm = red[(gg * 4 + 0) * BN + vs];
            mm = fminf(mm, red[(gg * 4 + 1) * BN + vs]);
            mm = fminf(mm, red[(gg * 4 + 2) * BN + vs]);
            mm = fminf(mm, red[(gg * 4 + 3) * BN + vs]);
            red2[gg * BN + vs] = mm;
            if (tid < BN) {
                float mmm = red2[0 * BN + tid];
                #pragma unroll
                for (int g2 = 1; g2 < 16; ++g2)
                    mmm = fminf(mmm, red2[g2 * BN + tid]);
                float newv = fminf(dprev_own, mmm);
                dcol[tid] = newv;
                AS(&D0[(s & 1) * NN + vb + tid], newv);
                ch = (newv != dprev_own) ? 1u : 0u;
                dprev_own = newv;
            }
        }
        unsigned long long bal = __ballot(ch != 0);   // wave0 lanes 0..3 matter
        if (tid == 0) {
            unsigned chown = (bal & 0xFull) ? 1u : 0u;
            asm volatile("s_waitcnt vmcnt(0)" ::: "memory");
            AS(&flags[b], ((unsigned)s << 1) | chown);
        }
        __syncthreads();                             // sync B (dcol ready)

        if (s < NN) {                                 // fold column s
            float dv = dcol[vown];
            acc0 = fmaf(dv, w0, acc0);
            acc1 = fmaf(dv, w1, acc1);
        }
        if (tid < 64) {
            unsigned chany = sweep_poll(flags, s);
            if (tid == 0) pinfo[0] = chany;
        }
        __syncthreads();                             // sync C
        unsigned chany = pinfo[0];
        if (!chany) { kconv = s; break; }             // fixed point reached
        if (s == NN) { hneg = 1; kconv = NN; break; } // probe still relaxing

        // ---- gather full new dist vector ----
        {
            const int sb = (s & 1);
            #pragma unroll
            for (int k = 0; k < NN / NTHR; ++k) {
                int i = tid + k * NTHR;
                dist[i] = AL(&D0[sb * NN + i]);
            }
        }
        __syncthreads();                             // sync D
    }

    // ---- tail: columns kconv+1 .. NN-1 all equal final dist ----
    if (kconv >= 1 && kconv < NN - 1 && !hneg) {
        const int wv = tid >> 6, lane = tid & 63;
        for (int r = 0; r < 32; ++r) {
            int c = 4 * r + wv;
            float ssum = 0.0f;
            for (int i = kconv + 1 + lane; i <= NN - 1; i += 64)
                ssum += W[(size_t)c * WROW + FF + i];
            #pragma unroll
            for (int st = 1; st < 64; st <<= 1)
                ssum += __shfl_xor(ssum, st, 64);
            if (lane == 0) Suf[c] = ssum;
        }
        __syncthreads();
        float dv = dcol[vown];
        acc0 = fmaf(dv, Suf[c0], acc0);
        acc1 = fmaf(dv, Suf[c0 + 1], acc1);
    }

    // ---- publish partials through out, then rendezvous ----
    AS(&out[(size_t)vglob * CC + c0], acc0);
    AS(&out[(size_t)vglob * CC + c0 + 1], acc1);
    asm volatile("s_waitcnt vmcnt(0)" ::: "memory");   // every wave drains its own
    __syncthreads();
    if (tid == 0) AS(&flags2[b], DONEV);

    if (b >= P2B) return;

    // ================= phase 2: out = partial + emb @ Wemb^T + bias =========
    float* Elds = (float*)smem;                  // [8][FF]   16384 B
    float* Wt   = (float*)(smem + 16384);        // [CC][34]  17408 B

    if (tid < 64) done_poll(flags2);
    __syncthreads();

    // stage E rows 8b..8b+8 (coalesced)
    #pragma unroll
    for (int qq = 0; qq < 4; ++qq) {
        int r = tid + 256 * qq;                  // 0..1023
        int v = r >> 7, i4 = (r & 127) * 4;
        float4 ev = *(const float4*)(emb + (size_t)(8 * b + v) * FF + i4);
        *(float4*)(Elds + v * FF + i4) = ev;
    }

    const int v2 = tid >> 5;                     // 0..7
    const int cg = tid & 31;                     // c = cg + 32j
    float acc[4];
    #pragma unroll
    for (int j = 0; j < 4; ++j)
        acc[j] = AL(&out[(size_t)(8 * b + v2) * CC + cg + 32 * j]);
    __syncthreads();

    for (int chk = 0; chk < FF / 32; ++chk) {
        // stage Wt[c][i] (c-major, row stride 34) for i in [32*chk, 32*chk+32)
        #pragma unroll
        for (int qq = 0; qq < 4; ++qq) {
            int r = tid + 256 * qq;              // 0..1023
            int c = r >> 3, i4 = (r & 7) * 4;
            float4 wv4 = *(const float4*)(W + (size_t)c * WROW + 32 * chk + i4);
            Wt[c * 34 + i4 + 0] = wv4.x;
            Wt[c * 34 + i4 + 1] = wv4.y;
            Wt[c * 34 + i4 + 2] = wv4.z;
            Wt[c * 34 + i4 + 3] = wv4.w;
        }
        __syncthreads();
        #pragma unroll
        for (int i = 0; i < 32; i += 2) {
            float2 e2 = *(float2*)(Elds + v2 * FF + 32 * chk + i);
            #pragma unroll
            for (int j = 0; j < 4; ++j) {
                float2 w2 = *(float2*)(Wt + (cg + 32 * j) * 34 + i);
                acc[j] = fmaf(e2.x, w2.x, acc[j]);
                acc[j] = fmaf(e2.y, w2.y, acc[j]);
            }
        }
        __syncthreads();
    }

    #pragma unroll
    for (int j = 0; j < 4; ++j) {
        int c = cg + 32 * j;
        out[(size_t)(8 * b + v2) * CC + c] = acc[j] + bias[c];
    }
    if (b == 0 && tid == 0 && out_size > NN * CC)
        out[NN * CC] = hneg ? 1.0f : 0.0f;
}

extern "C" void kernel_launch(void* const* d_in, const int* in_sizes, int n_in,
                              void* d_out, int out_size, void* d_ws, size_t ws_size,
                              hipStream_t stream) {
    const float* adj  = (const float*)d_in[0];
    const float* emb  = (const float*)d_in[1];
    const float* W    = (const float*)d_in[2];
    const float* bias = (const float*)d_in[3];
    const int*   srcp = (const int*)d_in[4];
    float* outp = (float*)d_out;
    unsigned* ws = (unsigned*)d_ws;
    int osz = out_size;

    void* args[] = { (void*)&adj, (void*)&emb, (void*)&W, (void*)&bias,
                     (void*)&srcp, (void*)&outp, (void*)&ws, (void*)&osz };
    hipLaunchCooperativeKernel((const void*)bf_gnn_lds,
                               dim3(NBLK), dim3(NTHR), args, 0, stream);
}